// Round 20
// baseline (57.128 us; speedup 1.0000x reference)
//
#include <hip/hip_runtime.h>
#include <hip/hip_bf16.h>

// GQA paged-prefill attention, MI355X gfx950.
// Causal mask j<=i over concat(past,new) => only first Q_LEN (=1024) gathered
// past tokens are live. Flash-attention over tokens 0..1023 of paged cache.
//
// R20 = R19 (lagged-PV reg pipeline) + V REMOVED FROM LDS: V^T fragments
// loaded directly from L2-resident ws into the lagged V registers, one
// iteration ahead. LDS = K-dbuf 32KB + P 8KB = 40KB; per-CU-tile LDS
// cycles roughly halve (the hypothesized limiter). exp2 softmax, setprio,
// counted vmcnt (20/16/4/0 at the pipeline edges).

#define NUM_HEADS 32
#define HEAD_DIM 128
#define Q_STRIDE 4096
// SCALE * log2(e): softmax computed in exp2 domain (v_exp_f32 is exp2).
#define SCALE2 0.1275179114285314f
#define RESCALE_THR 8.0f
#define KSW_TILE 16384                 // bytes per (hkv, jb) tile
#define VSW_OFF (2 * 1024 * 1024)      // linear V^T tiles start 2MB into ws

typedef short short8 __attribute__((ext_vector_type(8)));
typedef float f32x4 __attribute__((ext_vector_type(4)));
typedef unsigned short ushort_t;
typedef unsigned int uint_t;

__device__ __forceinline__ ushort_t f2bf(float f) {
    return __builtin_bit_cast(ushort_t, __float2bfloat16(f));
}
__device__ __forceinline__ uint_t pk2(float a, float b) {
    return (uint_t)f2bf(a) | ((uint_t)f2bf(b) << 16);
}

// ---------------- prep: paged fp32 -> dense bf16 (K swizzled, V^T linear) --
__launch_bounds__(256)
__global__ void prep_kv(const float* __restrict__ kvc,
                        const int* __restrict__ bt,
                        char* __restrict__ wsb)
{
    __shared__ float sVt[64 * 128];
    const int blk = blockIdx.x;        // 128 blocks = hkv(8) x jb(16)
    const int hkv = blk >> 4;
    const int jb  = blk & 15;
    const int tid = threadIdx.x;
    char* kout = wsb + (size_t)(hkv * 16 + jb) * KSW_TILE;
    char* vout = wsb + VSW_OFF + (size_t)(hkv * 16 + jb) * KSW_TILE;

    // K: [t 64][d 128] bf16, 16B chunk c at byte t*256 + ((c*16)^((t&7)<<4))
#pragma unroll
    for (int i = 0; i < 4; ++i) {
        const int u = tid + i * 256;   // t(64) x c(16)
        const int t = u >> 4, c = u & 15;
        const int gtok = jb * 64 + t;
        const int page = bt[gtok >> 4];
        const float* src = kvc + (size_t)page * 32768 + (size_t)hkv * 2048
                         + (gtok & 15) * 128 + c * 8;
        float4 a = *(const float4*)src;
        float4 b = *(const float4*)(src + 4);
        uint4 p;
        p.x = pk2(a.x, a.y); p.y = pk2(a.z, a.w);
        p.z = pk2(b.x, b.y); p.w = pk2(b.z, b.w);
        *(uint4*)(kout + t * 256 + ((c * 16) ^ ((t & 7) << 4))) = p;
    }
    // V: coalesced fp32 read -> LDS ([t][d])
#pragma unroll
    for (int i = 0; i < 8; ++i) {
        const int u = tid + i * 256;   // t(64) x c4(32)
        const int t = u >> 5, c4 = u & 31;
        const int gtok = jb * 64 + t;
        const int page = bt[gtok >> 4];
        const float* src = kvc + (size_t)page * 32768 + 16384
                         + (size_t)hkv * 2048 + (gtok & 15) * 128 + c4 * 4;
        *(float4*)(sVt + t * 128 + c4 * 4) = *(const float4*)src;
    }
    __syncthreads();
    // V^T: [d 128][t 64] bf16 LINEAR (read direct to regs in main)
#pragma unroll
    for (int i = 0; i < 4; ++i) {
        const int u = tid + i * 256;   // d(128) x ch(8)
        const int d = u >> 3, ch = u & 7;
        float v[8];
#pragma unroll
        for (int k = 0; k < 8; ++k) v[k] = sVt[(8 * ch + k) * 128 + d];
        uint4 p;
        p.x = pk2(v[0], v[1]); p.y = pk2(v[2], v[3]);
        p.z = pk2(v[4], v[5]); p.w = pk2(v[6], v[7]);
        *(uint4*)(vout + d * 128 + 16 * ch) = p;
    }
}

// ---------------- main attention ----------------
#define GLL16(G, L) __builtin_amdgcn_global_load_lds(                         \
    (const uint_t __attribute__((address_space(1)))*)(G),                     \
    (uint_t __attribute__((address_space(3)))*)(L), 16, 0, 0)

// Stage K tile JB only: 4 glls per wave (16KB block-wide).
#define STAGE_K(JB, KB) {                                                     \
    const char* ks = kvbf + (size_t)(hkv * 16 + (JB)) * KSW_TILE              \
                   + w * 4096 + lane * 16;                                    \
    _Pragma("unroll")                                                         \
    for (int i = 0; i < 4; ++i)                                               \
        GLL16(ks + i * 1024, (KB) + w * 4096 + i * 1024);                     \
}

__launch_bounds__(256)
__global__ void attn_main(const float* __restrict__ q,
                          const char* __restrict__ kvbf,
                          float* __restrict__ out)
{
    __shared__ __align__(16) char sK[2][16384];
    __shared__ __align__(16) char sP[4][2048];   // 40KB total

    const int bid = blockIdx.x;
    const int h   = bid & 31;
    const int qt  = 15 - (bid >> 5);   // long blocks first
    const int hkv = h >> 2;
    const int tid  = threadIdx.x;
    const int w    = tid >> 6;
    const int lane = tid & 63;
    const int l15  = lane & 15;
    const int lhi  = lane >> 4;

    // ---- Q fragments (SCALE2 folded -> exp2 domain)
    short8 qf[4];
    {
        const int qrow = qt * 64 + w * 16 + l15;
        const float* qp = q + (size_t)qrow * Q_STRIDE + h * HEAD_DIM;
#pragma unroll
        for (int s = 0; s < 4; ++s) {
            const int d0 = s * 32 + lhi * 8;
            float4 a = *(const float4*)(qp + d0);
            float4 b = *(const float4*)(qp + d0 + 4);
            short8 v;
            v[0] = (short)f2bf(a.x * SCALE2); v[1] = (short)f2bf(a.y * SCALE2);
            v[2] = (short)f2bf(a.z * SCALE2); v[3] = (short)f2bf(a.w * SCALE2);
            v[4] = (short)f2bf(b.x * SCALE2); v[5] = (short)f2bf(b.y * SCALE2);
            v[6] = (short)f2bf(b.z * SCALE2); v[7] = (short)f2bf(b.w * SCALE2);
            qf[s] = v;
        }
    }

    f32x4 acc[8];
#pragma unroll
    for (int n2 = 0; n2 < 8; ++n2) acc[n2] = (f32x4){0.f, 0.f, 0.f, 0.f};
    float m_run[4]  = {-1e30f, -1e30f, -1e30f, -1e30f};
    float l_part[4] = {0.f, 0.f, 0.f, 0.f};

    // lagged-PV register state: P fragments + V fragments of tile j-1
    short8 pap0, pap1;
    short8 vbp[2][8];

    // prologue: K tile 0 -> buf 0, full drain once
    STAGE_K(0, sK[0])
    __syncthreads();

    char* pb = sP[w];
    for (int jb = 0; jb <= qt; ++jb) {
        const int cur = jb & 1;
        char* kbuf = sK[cur];
        const bool pf = (jb < qt);
        // vmcnt accounting: ops newer than K_jb's 4 glls at the wait point:
        //   V_{jb-1} regs (16, absent when jb==0) + K_{jb+1} (4, when pf).
        if (pf) {
            STAGE_K(jb + 1, sK[cur ^ 1])
            if (jb == 0) { asm volatile("s_waitcnt vmcnt(4)" ::: "memory"); }
            else         { asm volatile("s_waitcnt vmcnt(20)" ::: "memory"); }
        } else {
            if (jb == 0) { asm volatile("s_waitcnt vmcnt(0)" ::: "memory"); }
            else         { asm volatile("s_waitcnt vmcnt(16)" ::: "memory"); }
        }
        __builtin_amdgcn_sched_barrier(0);
        __builtin_amdgcn_s_barrier();
        __builtin_amdgcn_sched_barrier(0);

        __builtin_amdgcn_s_setprio(1);
        // ---- lagged PV_{j-1}: register-only MFMAs (V came from L2 last iter)
        if (jb > 0) {
#pragma unroll
            for (int n2 = 0; n2 < 8; ++n2) {
                acc[n2] = __builtin_amdgcn_mfma_f32_16x16x32_bf16(pap0, vbp[0][n2], acc[n2], 0, 0, 0);
                acc[n2] = __builtin_amdgcn_mfma_f32_16x16x32_bf16(pap1, vbp[1][n2], acc[n2], 0, 0, 0);
            }
        }

        // ---- S = Q K^T (K from LDS)
        f32x4 sacc[4];
#pragma unroll
        for (int n = 0; n < 4; ++n) sacc[n] = (f32x4){0.f, 0.f, 0.f, 0.f};
#pragma unroll
        for (int s = 0; s < 4; ++s) {
#pragma unroll
            for (int n = 0; n < 4; ++n) {
                const int tok = n * 16 + l15;
                const uint_t byte = (uint_t)(tok * 256)
                    + (((uint_t)((s * 32 + lhi * 8) * 2)) ^ ((uint_t)((tok & 7) << 4)));
                short8 kb = *(const short8*)(kbuf + byte);
                sacc[n] = __builtin_amdgcn_mfma_f32_16x16x32_bf16(qf[s], kb, sacc[n], 0, 0, 0);
            }
        }
        __builtin_amdgcn_s_setprio(0);

        // ---- issue V_jb fragment loads DIRECT FROM L2 (linear V^T tile);
        // consumed next iteration -> a full iteration of latency slack.
        {
            const char* vt = kvbf + VSW_OFF + (size_t)(hkv * 16 + jb) * KSW_TILE;
#pragma unroll
            for (int n2 = 0; n2 < 8; ++n2) {
                const int dim = n2 * 16 + l15;
                vbp[0][n2] = *(const short8*)(vt + dim * 128 + lhi * 16);
                vbp[1][n2] = *(const short8*)(vt + dim * 128 + 64 + lhi * 16);
            }
        }

        // ---- softmax (exp2 domain) with deferred max
        const bool diag = (jb == qt);
        if (diag) {
#pragma unroll
            for (int n = 0; n < 4; ++n)
#pragma unroll
                for (int j = 0; j < 4; ++j) {
                    const int tok = jb * 64 + n * 16 + l15;
                    const int qg  = qt * 64 + w * 16 + lhi * 4 + j;
                    if (tok > qg) sacc[n][j] = -1e30f;
                }
        }
#pragma unroll
        for (int j = 0; j < 4; ++j) {
            float lmax = fmaxf(fmaxf(sacc[0][j], sacc[1][j]),
                               fmaxf(sacc[2][j], sacc[3][j]));
            if (__any(lmax > m_run[j] + RESCALE_THR)) {
                float mt = lmax;
#pragma unroll
                for (int off = 1; off < 16; off <<= 1)
                    mt = fmaxf(mt, __shfl_xor(mt, off));
                const float mn = fmaxf(m_run[j], mt);
                const float alpha = exp2f(m_run[j] - mn);
                m_run[j] = mn;
                l_part[j] *= alpha;
#pragma unroll
                for (int n2 = 0; n2 < 8; ++n2) acc[n2][j] *= alpha;
            }
            float ls = 0.f;
#pragma unroll
            for (int n = 0; n < 4; ++n) {
                float p = exp2f(sacc[n][j] - m_run[j]);
                sacc[n][j] = p;
                ls += p;
            }
            l_part[j] += ls;
        }

        // ---- P_j -> per-wave LDS (A-fragment relayout); same-wave ordering
#pragma unroll
        for (int n = 0; n < 4; ++n)
#pragma unroll
            for (int j = 0; j < 4; ++j) {
                const int r = lhi * 4 + j;
                const uint_t byte = (uint_t)(r * 128)
                    + (((uint_t)((n * 16 + l15) * 2)) ^ ((uint_t)((r & 7) << 4)));
                *(ushort_t*)(pb + byte) = f2bf(sacc[n][j]);
            }

        // ---- pull P_j A-fragments for next iteration's lagged PV
        {
            const uint_t pbyte0 = (uint_t)(l15 * 128)
                + (((uint_t)((lhi * 8) * 2)) ^ ((uint_t)((l15 & 7) << 4)));
            pap0 = *(const short8*)(pb + pbyte0);
            const uint_t pbyte1 = (uint_t)(l15 * 128)
                + (((uint_t)((32 + lhi * 8) * 2)) ^ ((uint_t)((l15 & 7) << 4)));
            pap1 = *(const short8*)(pb + pbyte1);
        }

        if (pf) {
            __builtin_amdgcn_sched_barrier(0);
            __builtin_amdgcn_s_barrier();   // guards sK overwrite next iter
            __builtin_amdgcn_sched_barrier(0);
        }
    }

    // ---- final lagged PV (last tile); compiler inserts waits for pap/vbp
    asm volatile("s_waitcnt lgkmcnt(0)" ::: "memory");
    __builtin_amdgcn_sched_barrier(0);
#pragma unroll
    for (int n2 = 0; n2 < 8; ++n2) {
        acc[n2] = __builtin_amdgcn_mfma_f32_16x16x32_bf16(pap0, vbp[0][n2], acc[n2], 0, 0, 0);
        acc[n2] = __builtin_amdgcn_mfma_f32_16x16x32_bf16(pap1, vbp[1][n2], acc[n2], 0, 0, 0);
    }

    // ---- epilogue: reduce per-lane l across 16-lane row group, store
#pragma unroll
    for (int j = 0; j < 4; ++j) {
        float lsum = l_part[j];
#pragma unroll
        for (int off = 1; off < 16; off <<= 1)
            lsum += __shfl_xor(lsum, off);
        const float inv = 1.0f / lsum;
        const int qg = qt * 64 + w * 16 + lhi * 4 + j;
        float* dst = out + (size_t)qg * Q_STRIDE + h * HEAD_DIM;
#pragma unroll
        for (int n2 = 0; n2 < 8; ++n2)
            dst[n2 * 16 + l15] = acc[n2][j] * inv;
    }
}

extern "C" void kernel_launch(void* const* d_in, const int* in_sizes, int n_in,
                              void* d_out, int out_size, void* d_ws, size_t ws_size,
                              hipStream_t stream) {
    const float* q   = (const float*)d_in[0];
    // d_in[1] (k) and d_in[2] (v) are dead under the reference's causal mask.
    const float* kvc = (const float*)d_in[3];
    const int*   bt  = (const int*)d_in[4];
    float* out = (float*)d_out;
    char*  wsb = (char*)d_ws;
    prep_kv<<<dim3(128), dim3(256), 0, stream>>>(kvc, bt, wsb);
    attn_main<<<dim3(512), dim3(256), 0, stream>>>(q, wsb, out);
}